// Round 1
// baseline (130.608 us; speedup 1.0000x reference)
//
#include <hip/hip_runtime.h>
#include <math.h>

// Problem constants (fixed shapes from setup_inputs):
//   pred_logits [16,900,151] f32, pred_boxes [16,900,4] f32,
//   tgt_labels  [16,100] i32,     tgt_boxes  [16,100,4] f32
//   out C [16,900,1600] f32  (rows r = b*900+q, cols t = concat targets)
#define NROWS 14400   // 16*900
#define NT    1600    // 16*100
#define NC    151
#define ROWS_PER_BLOCK 32

// ---------------------------------------------------------------------------
// Kernel 1: per-row prep. One wave (64 lanes) per query row.
//   - softmax stats over 151 classes: rmax, rinv = 1/sum(exp(x-rmax))
//   - pred box cxcywh -> xyxy + area
// Packed 12 floats per row into ws:
//   [0..3]  cx,cy,w,h   [4..7] x0,y0,x1,y1   [8..10] area,rmax,rinv  [11] pad
// ---------------------------------------------------------------------------
__global__ __launch_bounds__(256) void row_prep(
    const float* __restrict__ logits,
    const float* __restrict__ pboxes,
    float* __restrict__ rowdata)
{
    const int wave = threadIdx.x >> 6;
    const int lane = threadIdx.x & 63;
    const int r = blockIdx.x * 4 + wave;            // grid 3600 * 4 = 14400 exact

    const float* row = logits + (size_t)r * NC;
    // lanes cover classes {l, l+64, l+128}; 151 = 64 + 64 + 23
    float v0 = row[lane];
    float v1 = row[lane + 64];
    float v2 = (lane < NC - 128) ? row[lane + 128] : -3.4e38f;

    float m = fmaxf(fmaxf(v0, v1), v2);
    #pragma unroll
    for (int off = 32; off; off >>= 1) m = fmaxf(m, __shfl_xor(m, off, 64));

    float s = __expf(v0 - m) + __expf(v1 - m) +
              ((lane < NC - 128) ? __expf(v2 - m) : 0.0f);
    #pragma unroll
    for (int off = 32; off; off >>= 1) s += __shfl_xor(s, off, 64);

    if (lane == 0) {
        float4 pb = ((const float4*)pboxes)[r];
        float x0 = pb.x - 0.5f * pb.z, y0 = pb.y - 0.5f * pb.w;
        float x1 = pb.x + 0.5f * pb.z, y1 = pb.y + 0.5f * pb.w;
        float area = (x1 - x0) * (y1 - y0);   // match reference (area from xyxy)
        float* o = rowdata + (size_t)r * 12;
        ((float4*)o)[0] = make_float4(pb.x, pb.y, pb.z, pb.w);
        ((float4*)o)[1] = make_float4(x0, y0, x1, y1);
        ((float4*)o)[2] = make_float4(area, m, 1.0f / s, 0.0f);
    }
}

// ---------------------------------------------------------------------------
// Kernel 2: main cost matrix. Lanes map to targets (coalesced stores along t).
// block = 320 threads (5 waves); grid.x = 5 -> covers T=1600 with no tail.
// Each block iterates ROWS_PER_BLOCK rows; per-row data is wave-uniform
// (3 float4 loads from rowdata), target data lives in registers.
// ---------------------------------------------------------------------------
__global__ __launch_bounds__(320) void cost_kernel(
    const float* __restrict__ logits,
    const int*   __restrict__ tlabels,
    const float* __restrict__ tboxes,
    const float* __restrict__ rowdata,
    float* __restrict__ out)
{
    const int t = blockIdx.x * 320 + threadIdx.x;   // < 1600 always

    float4 tb = ((const float4*)tboxes)[t];         // cx,cy,w,h
    const int label = tlabels[t];
    const float tx0 = tb.x - 0.5f * tb.z, ty0 = tb.y - 0.5f * tb.w;
    const float tx1 = tb.x + 0.5f * tb.z, ty1 = tb.y + 0.5f * tb.w;
    const float tarea = (tx1 - tx0) * (ty1 - ty0);

    const int r0 = blockIdx.y * ROWS_PER_BLOCK;
    #pragma unroll 4
    for (int i = 0; i < ROWS_PER_BLOCK; ++i) {
        const int r = r0 + i;
        const float4* rd = (const float4*)(rowdata + (size_t)r * 12);
        const float4 pb  = rd[0];                   // cx,cy,w,h
        const float4 pxy = rd[1];                   // x0,y0,x1,y1
        const float4 ps  = rd[2];                   // area, rmax, rinv

        // cost_class = -softmax(logits)[r, label]
        const float lg  = logits[(size_t)r * NC + label];
        const float cls = __expf(lg - ps.y) * ps.z;

        // cost_bbox: L1 in cxcywh space
        const float l1 = fabsf(pb.x - tb.x) + fabsf(pb.y - tb.y) +
                         fabsf(pb.z - tb.z) + fabsf(pb.w - tb.w);

        // GIoU in xyxy space
        const float iw = fmaxf(fminf(pxy.z, tx1) - fmaxf(pxy.x, tx0), 0.0f);
        const float ih = fmaxf(fminf(pxy.w, ty1) - fmaxf(pxy.y, ty0), 0.0f);
        const float inter = iw * ih;
        const float uni   = ps.x + tarea - inter;
        const float iou   = inter * __builtin_amdgcn_rcpf(uni);
        const float ew = fmaxf(fmaxf(pxy.z, tx1) - fminf(pxy.x, tx0), 0.0f);
        const float eh = fmaxf(fmaxf(pxy.w, ty1) - fminf(pxy.y, ty0), 0.0f);
        const float earea = ew * eh;
        const float giou  = iou - (earea - uni) * __builtin_amdgcn_rcpf(earea);

        // C = 5*l1 + 1*(-prob) + 2*(-giou)
        out[(size_t)r * NT + t] = 5.0f * l1 - cls - 2.0f * giou;
    }
}

extern "C" void kernel_launch(void* const* d_in, const int* in_sizes, int n_in,
                              void* d_out, int out_size, void* d_ws, size_t ws_size,
                              hipStream_t stream) {
    const float* logits  = (const float*)d_in[0];   // [14400,151]
    const float* pboxes  = (const float*)d_in[1];   // [14400,4]
    const int*   tlabels = (const int*)d_in[2];     // [1600]
    const float* tboxes  = (const float*)d_in[3];   // [1600,4]
    float* out = (float*)d_out;                     // [14400,1600]
    float* rowdata = (float*)d_ws;                  // needs 14400*12*4 = 691200 B

    row_prep<<<dim3(NROWS / 4), 256, 0, stream>>>(logits, pboxes, rowdata);
    cost_kernel<<<dim3(5, NROWS / ROWS_PER_BLOCK), 320, 0, stream>>>(
        logits, tlabels, tboxes, rowdata, out);
}